// Round 5
// baseline (1289.501 us; speedup 1.0000x reference)
//
#include <hip/hip_runtime.h>

#define DD 64
constexpr int N_P   = 100000;
constexpr int N_G   = 40000;
constexpr int NE    = 1600000;
constexpr int E_LBL = 500000;
constexpr int F_GO  = 1000;

typedef __attribute__((ext_vector_type(8))) short bf16x8;
typedef __attribute__((ext_vector_type(4))) float f32x4;
typedef __attribute__((ext_vector_type(4))) short s16x4;

// ---- fp32 -> bf16 hi/lo split (RNE) ----
__device__ __forceinline__ unsigned short f2bf_rne(float x) {
    unsigned u = __float_as_uint(x);
    u += 0x7fff + ((u >> 16) & 1);
    return (unsigned short)(u >> 16);
}
__device__ __forceinline__ float bf2f(unsigned short h) {
    return __uint_as_float((unsigned)h << 16);
}
struct BfPair { short h; short l; };
__device__ __forceinline__ BfPair split_bf(float x) {
    BfPair p;
    unsigned short hh = f2bf_rne(x);
    unsigned short ll = f2bf_rne(x - bf2f(hh));
    p.h = (short)hh; p.l = (short)ll;
    return p;
}

// ---------------- gather rows: out[i] = emb[nid[i]] ----------------
__global__ void gather_rows(const float* __restrict__ emb, const int* __restrict__ nid,
                            float* __restrict__ out, int n) {
    int t = blockIdx.x * blockDim.x + threadIdx.x;
    int total = n * (DD / 4);
    if (t >= total) return;
    int row = t / (DD / 4);
    int c4  = t % (DD / 4);
    int srow = nid[row];
    reinterpret_cast<float4*>(out)[(size_t)row * (DD / 4) + c4] =
        reinterpret_cast<const float4*>(emb)[(size_t)srow * (DD / 4) + c4];
}

// ---------------- xg = go_x @ lin_W + lin_b + go_emb[go_nid] (bf16x3 MFMA) ----
// 128x64 block tile, 4 waves; wave = 32 rows x 64 cols; K tiled by 64.
constexpr int LDA_LG = 72;   // 144B row stride: 16B-aligned, 2-way banks (free)
__global__ __launch_bounds__(256) void lin_go_mfma(const float* __restrict__ go_x,
        const float* __restrict__ lin_W, const float* __restrict__ lin_b,
        const float* __restrict__ go_emb, const int* __restrict__ go_nid,
        float* __restrict__ out) {
    __shared__ short Ah[128][LDA_LG], Al[128][LDA_LG];
    __shared__ short Bh[64][LDA_LG],  Bl[64][LDA_LG];
    int tid = threadIdx.x;
    int wave = tid >> 6, lane = tid & 63;
    int ml = lane & 15, q = lane >> 4;
    int row0 = blockIdx.x * 128;
    f32x4 acc[2][4] = {};
    for (int k0 = 0; k0 < F_GO; k0 += 64) {
        // stage A: 128 rows x 64 ks (fp32 -> hi/lo bf16), zero-pad past K=1000
        {
            int k4 = tid & 15;
            int kk = k0 + k4 * 4;
            bool valid = (kk < F_GO);       // F_GO % 4 == 0
            for (int r = tid >> 4; r < 128; r += 16) {
                int grow = row0 + r; if (grow > N_G - 1) grow = N_G - 1;
                float4 v = make_float4(0.f, 0.f, 0.f, 0.f);
                if (valid) v = *reinterpret_cast<const float4*>(&go_x[(size_t)grow * F_GO + kk]);
                s16x4 h, l;
                BfPair p0 = split_bf(v.x), p1 = split_bf(v.y),
                       p2 = split_bf(v.z), p3 = split_bf(v.w);
                h[0] = p0.h; h[1] = p1.h; h[2] = p2.h; h[3] = p3.h;
                l[0] = p0.l; l[1] = p1.l; l[2] = p2.l; l[3] = p3.l;
                *reinterpret_cast<s16x4*>(&Ah[r][k4 * 4]) = h;
                *reinterpret_cast<s16x4*>(&Al[r][k4 * 4]) = l;
            }
        }
        // stage B^T: Bh[n][k] = lin_W[k0+k][n]
        {
            int nn = tid & 63;
            for (int kr = tid >> 6; kr < 64; kr += 4) {
                int kk = k0 + kr;
                float v = (kk < F_GO) ? lin_W[(size_t)kk * 64 + nn] : 0.f;
                BfPair p = split_bf(v);
                Bh[nn][kr] = p.h; Bl[nn][kr] = p.l;
            }
        }
        __syncthreads();
#pragma unroll
        for (int kc = 0; kc < 64; kc += 32) {
            int kb = kc + q * 8;
            bf16x8 ah[2], al[2], bh[4], bl[4];
#pragma unroll
            for (int mt = 0; mt < 2; ++mt) {
                int m = wave * 32 + mt * 16 + ml;
                ah[mt] = *reinterpret_cast<const bf16x8*>(&Ah[m][kb]);
                al[mt] = *reinterpret_cast<const bf16x8*>(&Al[m][kb]);
            }
#pragma unroll
            for (int nt = 0; nt < 4; ++nt) {
                int nn = nt * 16 + ml;
                bh[nt] = *reinterpret_cast<const bf16x8*>(&Bh[nn][kb]);
                bl[nt] = *reinterpret_cast<const bf16x8*>(&Bl[nn][kb]);
            }
#pragma unroll
            for (int mt = 0; mt < 2; ++mt)
#pragma unroll
                for (int nt = 0; nt < 4; ++nt) {
                    acc[mt][nt] = __builtin_amdgcn_mfma_f32_16x16x32_bf16(ah[mt], bh[nt], acc[mt][nt], 0, 0, 0);
                    acc[mt][nt] = __builtin_amdgcn_mfma_f32_16x16x32_bf16(al[mt], bh[nt], acc[mt][nt], 0, 0, 0);
                    acc[mt][nt] = __builtin_amdgcn_mfma_f32_16x16x32_bf16(ah[mt], bl[nt], acc[mt][nt], 0, 0, 0);
                }
        }
        __syncthreads();
    }
    // epilogue: C/D layout col=lane&15, row=quad*4+reg
#pragma unroll
    for (int mt = 0; mt < 2; ++mt) {
#pragma unroll
        for (int reg = 0; reg < 4; ++reg) {
            int row = row0 + wave * 32 + mt * 16 + q * 4 + reg;
            if (row >= N_G) continue;
            int nid = go_nid[row];
#pragma unroll
            for (int nt = 0; nt < 4; ++nt) {
                int col = nt * 16 + ml;
                out[(size_t)row * 64 + col] = acc[mt][nt][reg] + lin_b[col]
                    + go_emb[(size_t)nid * 64 + col];
            }
        }
    }
}

// ---------------- CSR build ----------------
__global__ void count_int(const int* __restrict__ dst, int* __restrict__ cnt, int nE) {
    int e = blockIdx.x * blockDim.x + threadIdx.x;
    if (e < nE) atomicAdd(&cnt[dst[e]], 1);
}

__global__ __launch_bounds__(1024) void scan_local(const int* __restrict__ cnt,
        int* __restrict__ loc, int* __restrict__ bsum, int n) {
    __shared__ int sh[1024];
    int i = blockIdx.x * 1024 + threadIdx.x;
    int v = (i < n) ? cnt[i] : 0;
    sh[threadIdx.x] = v;
    __syncthreads();
    for (int off = 1; off < 1024; off <<= 1) {
        int t = (threadIdx.x >= off) ? sh[threadIdx.x - off] : 0;
        __syncthreads();
        sh[threadIdx.x] += t;
        __syncthreads();
    }
    if (i < n) loc[i] = sh[threadIdx.x] - v;
    if (threadIdx.x == 1023) bsum[blockIdx.x] = sh[1023];
}

__global__ __launch_bounds__(1024) void scan_bsum(int* __restrict__ bsum, int nb) {
    __shared__ int sh[1024];
    int v = (threadIdx.x < nb) ? bsum[threadIdx.x] : 0;
    sh[threadIdx.x] = v;
    __syncthreads();
    for (int off = 1; off < 1024; off <<= 1) {
        int t = (threadIdx.x >= off) ? sh[threadIdx.x - off] : 0;
        __syncthreads();
        sh[threadIdx.x] += t;
        __syncthreads();
    }
    if (threadIdx.x < nb) bsum[threadIdx.x] = sh[threadIdx.x] - v;
}

__global__ void scan_add(const int* __restrict__ loc, const int* __restrict__ bsum,
                         int* __restrict__ rowptr, int* __restrict__ cursor, int n, int total) {
    int i = blockIdx.x * blockDim.x + threadIdx.x;
    if (i < n) {
        int v = loc[i] + bsum[i >> 10];
        rowptr[i] = v;
        cursor[i] = v;
    }
    if (i == n) rowptr[n] = total;
}

__global__ void fill_csr(const int* __restrict__ src, const int* __restrict__ dst,
                         int* __restrict__ cursor, int* __restrict__ csr_src, int nE) {
    int e = blockIdx.x * blockDim.x + threadIdx.x;
    if (e >= nE) return;
    int slot = atomicAdd(&cursor[dst[e]], 1);
    csr_src[slot] = src[e];
}

// ---------------- aggregation: out[d] = mean over CSR edges of x[src] ----------
__global__ void aggregate_csr(const float* __restrict__ x, const int* __restrict__ rowptr,
                              const int* __restrict__ csr_src, float* __restrict__ out, int n) {
    int row = blockIdx.x * 4 + (threadIdx.x >> 6);
    if (row >= n) return;
    int lane = threadIdx.x & 63;
    int qg   = lane >> 4;
    int l16  = lane & 15;
    int s = rowptr[row], e = rowptr[row + 1];
    const float4* x4 = reinterpret_cast<const float4*>(x);
    float4 a0 = make_float4(0.f, 0.f, 0.f, 0.f);
    float4 a1 = make_float4(0.f, 0.f, 0.f, 0.f);
    int i = s + qg;
    for (; i + 4 < e; i += 8) {
        int s0 = csr_src[i];
        int s1 = csr_src[i + 4];
        float4 v0 = x4[(size_t)s0 * 16 + l16];
        float4 v1 = x4[(size_t)s1 * 16 + l16];
        a0.x += v0.x; a0.y += v0.y; a0.z += v0.z; a0.w += v0.w;
        a1.x += v1.x; a1.y += v1.y; a1.z += v1.z; a1.w += v1.w;
    }
    if (i < e) {
        int s0 = csr_src[i];
        float4 v0 = x4[(size_t)s0 * 16 + l16];
        a0.x += v0.x; a0.y += v0.y; a0.z += v0.z; a0.w += v0.w;
    }
    a0.x += a1.x; a0.y += a1.y; a0.z += a1.z; a0.w += a1.w;
    a0.x += __shfl_xor(a0.x, 16); a0.y += __shfl_xor(a0.y, 16);
    a0.z += __shfl_xor(a0.z, 16); a0.w += __shfl_xor(a0.w, 16);
    a0.x += __shfl_xor(a0.x, 32); a0.y += __shfl_xor(a0.y, 32);
    a0.z += __shfl_xor(a0.z, 32); a0.w += __shfl_xor(a0.w, 32);
    if (qg == 0) {
        float inv = (e > s) ? 1.0f / (float)(e - s) : 0.0f;
        float4 r = make_float4(a0.x * inv, a0.y * inv, a0.z * inv, a0.w * inv);
        reinterpret_cast<float4*>(out)[(size_t)row * 16 + l16] = r;
    }
}

// ---------------- node update: out = agg@Wl + bias + x@Wr (bf16x3 MFMA) ----
// 64-row block, 4 waves; wave = 16 rows x 64 cols. Two halves: (agg,Wl), (x,Wr).
constexpr int LDA_UN = 72;
__global__ __launch_bounds__(256) void update_nodes_mfma(
        const float* agg, const float* __restrict__ x,
        const float* __restrict__ Wl, const float* __restrict__ bias,
        const float* __restrict__ Wr, float* out, int n, int relu) {
    __shared__ short Ah[64][LDA_UN], Al[64][LDA_UN];
    __shared__ short Bh[64][LDA_UN], Bl[64][LDA_UN];
    int tid = threadIdx.x;
    int wave = tid >> 6, lane = tid & 63;
    int ml = lane & 15, q = lane >> 4;
    int row0 = blockIdx.x * 64;
    f32x4 acc[4] = {};
    for (int half = 0; half < 2; ++half) {
        const float* Xsrc = half ? x : agg;
        const float* Wsrc = half ? Wr : Wl;
        {
            int k4 = tid & 15;
            for (int r = tid >> 4; r < 64; r += 16) {
                int grow = row0 + r; if (grow >= n) grow = n - 1;
                float4 v = *reinterpret_cast<const float4*>(&Xsrc[(size_t)grow * 64 + k4 * 4]);
                s16x4 h, l;
                BfPair p0 = split_bf(v.x), p1 = split_bf(v.y),
                       p2 = split_bf(v.z), p3 = split_bf(v.w);
                h[0] = p0.h; h[1] = p1.h; h[2] = p2.h; h[3] = p3.h;
                l[0] = p0.l; l[1] = p1.l; l[2] = p2.l; l[3] = p3.l;
                *reinterpret_cast<s16x4*>(&Ah[r][k4 * 4]) = h;
                *reinterpret_cast<s16x4*>(&Al[r][k4 * 4]) = l;
            }
        }
        {
            int nn = tid & 63;
            for (int kr = tid >> 6; kr < 64; kr += 4) {
                float v = Wsrc[(size_t)kr * 64 + nn];
                BfPair p = split_bf(v);
                Bh[nn][kr] = p.h; Bl[nn][kr] = p.l;
            }
        }
        __syncthreads();
#pragma unroll
        for (int kc = 0; kc < 64; kc += 32) {
            int kb = kc + q * 8;
            int m = wave * 16 + ml;
            bf16x8 ah = *reinterpret_cast<const bf16x8*>(&Ah[m][kb]);
            bf16x8 al = *reinterpret_cast<const bf16x8*>(&Al[m][kb]);
#pragma unroll
            for (int nt = 0; nt < 4; ++nt) {
                int nn = nt * 16 + ml;
                bf16x8 bh = *reinterpret_cast<const bf16x8*>(&Bh[nn][kb]);
                bf16x8 bl = *reinterpret_cast<const bf16x8*>(&Bl[nn][kb]);
                acc[nt] = __builtin_amdgcn_mfma_f32_16x16x32_bf16(ah, bh, acc[nt], 0, 0, 0);
                acc[nt] = __builtin_amdgcn_mfma_f32_16x16x32_bf16(al, bh, acc[nt], 0, 0, 0);
                acc[nt] = __builtin_amdgcn_mfma_f32_16x16x32_bf16(ah, bl, acc[nt], 0, 0, 0);
            }
        }
        __syncthreads();
    }
#pragma unroll
    for (int reg = 0; reg < 4; ++reg) {
        int row = row0 + wave * 16 + q * 4 + reg;
        if (row >= n) continue;
#pragma unroll
        for (int nt = 0; nt < 4; ++nt) {
            int col = nt * 16 + ml;
            float v = acc[nt][reg] + bias[col];
            if (relu) v = fmaxf(v, 0.0f);
            out[(size_t)row * 64 + col] = v;
        }
    }
}

// ---------------- classifier ----------------
__global__ void classify(const float* __restrict__ xp, const float* __restrict__ xg,
                         const int* __restrict__ ls, const int* __restrict__ ld,
                         float* __restrict__ out, int nE) {
    int t = blockIdx.x * blockDim.x + threadIdx.x;
    int e = t >> 4;
    int l16 = t & 15;
    if (e >= nE) return;
    int s = ls[e], d = ld[e];
    float4 a = reinterpret_cast<const float4*>(xp)[(size_t)s * 16 + l16];
    float4 b = reinterpret_cast<const float4*>(xg)[(size_t)d * 16 + l16];
    float v = a.x * b.x + a.y * b.y + a.z * b.z + a.w * b.w;
    v += __shfl_xor(v, 8);
    v += __shfl_xor(v, 4);
    v += __shfl_xor(v, 2);
    v += __shfl_xor(v, 1);
    if (l16 == 0) out[e] = v;
}

extern "C" void kernel_launch(void* const* d_in, const int* in_sizes, int n_in,
                              void* d_out, int out_size, void* d_ws, size_t ws_size,
                              hipStream_t stream) {
    const float* go_x        = (const float*)d_in[0];
    const float* protein_emb = (const float*)d_in[1];
    const float* go_emb      = (const float*)d_in[2];
    const float* lin_W       = (const float*)d_in[3];
    const float* lin_b       = (const float*)d_in[4];
    const float* Wl          = (const float*)d_in[5];
    const float* bl          = (const float*)d_in[6];
    const float* Wr          = (const float*)d_in[7];
    const int* protein_nid   = (const int*)d_in[8];
    const int* go_nid        = (const int*)d_in[9];
    const int* src_pg        = (const int*)d_in[10];
    const int* dst_pg        = (const int*)d_in[11];
    const int* src_gp        = (const int*)d_in[12];
    const int* dst_gp        = (const int*)d_in[13];
    const int* label_src     = (const int*)d_in[14];
    const int* label_dst     = (const int*)d_in[15];
    float* out = (float*)d_out;

    float* ws = (float*)d_ws;
    float* p0 = ws;
    float* p1 = p0 + (size_t)N_P * 64;
    float* g0 = p1 + (size_t)N_P * 64;
    float* g1 = g0 + (size_t)N_G * 64;
    int* ib = (int*)(g1 + (size_t)N_G * 64);
    int* rowptr_g = ib;                 ib += N_G + 1;
    int* cursor_g = ib;                 ib += N_G + 1;
    int* rowptr_p = ib;                 ib += N_P + 1;
    int* cursor_p = ib;                 ib += N_P + 1;
    int* cnt_i    = ib;                 ib += N_P;
    int* loc      = ib;                 ib += N_P;
    int* bsum     = ib;                 ib += 1024;
    int* csr_g    = ib;                 ib += NE;
    int* csr_p    = ib;                 ib += NE;

    gather_rows<<<(N_P * (DD / 4) + 255) / 256, 256, 0, stream>>>(protein_emb, protein_nid, p0, N_P);
    lin_go_mfma<<<(N_G + 127) / 128, 256, 0, stream>>>(go_x, lin_W, lin_b, go_emb, go_nid, g0);

    hipMemsetAsync(cnt_i, 0, (size_t)N_G * sizeof(int), stream);
    count_int<<<(NE + 255) / 256, 256, 0, stream>>>(dst_pg, cnt_i, NE);
    scan_local<<<(N_G + 1023) / 1024, 1024, 0, stream>>>(cnt_i, loc, bsum, N_G);
    scan_bsum<<<1, 1024, 0, stream>>>(bsum, (N_G + 1023) / 1024);
    scan_add<<<(N_G + 256) / 256, 256, 0, stream>>>(loc, bsum, rowptr_g, cursor_g, N_G, NE);
    fill_csr<<<(NE + 255) / 256, 256, 0, stream>>>(src_pg, dst_pg, cursor_g, csr_g, NE);

    hipMemsetAsync(cnt_i, 0, (size_t)N_P * sizeof(int), stream);
    count_int<<<(NE + 255) / 256, 256, 0, stream>>>(dst_gp, cnt_i, NE);
    scan_local<<<(N_P + 1023) / 1024, 1024, 0, stream>>>(cnt_i, loc, bsum, N_P);
    scan_bsum<<<1, 1024, 0, stream>>>(bsum, (N_P + 1023) / 1024);
    scan_add<<<(N_P + 256) / 256, 256, 0, stream>>>(loc, bsum, rowptr_p, cursor_p, N_P, NE);
    fill_csr<<<(NE + 255) / 256, 256, 0, stream>>>(src_gp, dst_gp, cursor_p, csr_p, NE);

    float* xp = p0; float* xg = g0; float* sp = p1; float* sg = g1;
    for (int l = 0; l < 3; ++l) {
        aggregate_csr<<<(N_G + 3) / 4, 256, 0, stream>>>(xp, rowptr_g, csr_g, sg, N_G);
        aggregate_csr<<<(N_P + 3) / 4, 256, 0, stream>>>(xg, rowptr_p, csr_p, sp, N_P);
        int relu = (l < 2) ? 1 : 0;
        const float* wl0 = Wl + (size_t)(l * 2 + 0) * 4096;
        const float* wl1 = Wl + (size_t)(l * 2 + 1) * 4096;
        const float* wr0 = Wr + (size_t)(l * 2 + 0) * 4096;
        const float* wr1 = Wr + (size_t)(l * 2 + 1) * 4096;
        const float* b0  = bl + (size_t)(l * 2 + 0) * 64;
        const float* b1  = bl + (size_t)(l * 2 + 1) * 64;
        update_nodes_mfma<<<(N_G + 63) / 64, 256, 0, stream>>>(sg, xg, wl0, b0, wr0, sg, N_G, relu);
        update_nodes_mfma<<<(N_P + 63) / 64, 256, 0, stream>>>(sp, xp, wl1, b1, wr1, sp, N_P, relu);
        float* t;
        t = xp; xp = sp; sp = t;
        t = xg; xg = sg; sg = t;
    }
    classify<<<(E_LBL * 16 + 255) / 256, 256, 0, stream>>>(xp, xg, label_src, label_dst, out, E_LBL);
}

// Round 6
// 1188.839 us; speedup vs baseline: 1.0847x; 1.0847x over previous
//
#include <hip/hip_runtime.h>

#define DD 64
constexpr int N_P   = 100000;
constexpr int N_G   = 40000;
constexpr int NE    = 1600000;
constexpr int E_LBL = 500000;
constexpr int F_GO  = 1000;
constexpr int KSTEPS = 32;     // K padded to 1024 = 32 steps of 32

typedef __attribute__((ext_vector_type(8))) short bf16x8;
typedef __attribute__((ext_vector_type(4))) float f32x4;
typedef __attribute__((ext_vector_type(4))) short s16x4;

// ---- fp32 -> bf16 hi/lo split (RNE) ----
__device__ __forceinline__ unsigned short f2bf_rne(float x) {
    unsigned u = __float_as_uint(x);
    u += 0x7fff + ((u >> 16) & 1);
    return (unsigned short)(u >> 16);
}
__device__ __forceinline__ float bf2f(unsigned short h) {
    return __uint_as_float((unsigned)h << 16);
}
struct BfPair { short h; short l; };
__device__ __forceinline__ BfPair split_bf(float x) {
    BfPair p;
    unsigned short hh = f2bf_rne(x);
    unsigned short ll = f2bf_rne(x - bf2f(hh));
    p.h = (short)hh; p.l = (short)ll;
    return p;
}

// ---------------- gather rows: out[i] = emb[nid[i]] ----------------
__global__ void gather_rows(const float* __restrict__ emb, const int* __restrict__ nid,
                            float* __restrict__ out, int n) {
    int t = blockIdx.x * blockDim.x + threadIdx.x;
    int total = n * (DD / 4);
    if (t >= total) return;
    int row = t / (DD / 4);
    int c4  = t % (DD / 4);
    int srow = nid[row];
    reinterpret_cast<float4*>(out)[(size_t)row * (DD / 4) + c4] =
        reinterpret_cast<const float4*>(emb)[(size_t)srow * (DD / 4) + c4];
}

// ---------------- pack lin_W into MFMA B-fragment order, hi/lo bf16 ----------
// idx(s,n,q,j) = (((s*64+n)*4+q)*8+j);  value = lin_W[k= s*32+q*8+j][n], 0 if k>=1000
__global__ void pack_B(const float* __restrict__ lin_W,
                       short* __restrict__ BH, short* __restrict__ BL) {
    int t = blockIdx.x * blockDim.x + threadIdx.x;
    if (t >= KSTEPS * 64 * 4) return;
    int s = t >> 8, n = (t >> 2) & 63, q = t & 3;
    int base = t * 8;
#pragma unroll
    for (int j = 0; j < 8; ++j) {
        int k = s * 32 + q * 8 + j;
        float v = (k < F_GO) ? lin_W[(size_t)k * 64 + n] : 0.f;
        BfPair p = split_bf(v);
        BH[base + j] = p.h;
        BL[base + j] = p.l;
    }
}

// ---------------- xg = go_x @ lin_W + lin_b + go_emb[go_nid] ----------------
// No LDS, no barriers. Wave = 16 rows x 64 cols; block = 4 waves = 64 rows.
// A fragments loaded straight from go_x (converted in regs); B from packed array.
__global__ __launch_bounds__(256) void lin_go_mfma(const float* __restrict__ go_x,
        const short* __restrict__ BH, const short* __restrict__ BL,
        const float* __restrict__ lin_b, const float* __restrict__ go_emb,
        const int* __restrict__ go_nid, float* __restrict__ out) {
    int tid = threadIdx.x;
    int wave = tid >> 6, lane = tid & 63;
    int ml = lane & 15, q = lane >> 4;
    int row0 = blockIdx.x * 64 + wave * 16;      // grid 625 * 64 = 40000 exactly
    const float* arow = go_x + (size_t)(row0 + ml) * F_GO;
    f32x4 acc[4] = {};
    for (int s = 0; s < KSTEPS; ++s) {
        int kb = s * 32 + q * 8;
        int kc = kb > 992 ? 992 : kb;            // clamp tail: B is zero there anyway
        float4 va = *reinterpret_cast<const float4*>(arow + kc);
        float4 vb = *reinterpret_cast<const float4*>(arow + kc + 4);
        bf16x8 ah, al;
        {
            BfPair p0 = split_bf(va.x), p1 = split_bf(va.y),
                   p2 = split_bf(va.z), p3 = split_bf(va.w);
            BfPair p4 = split_bf(vb.x), p5 = split_bf(vb.y),
                   p6 = split_bf(vb.z), p7 = split_bf(vb.w);
            ah[0]=p0.h; ah[1]=p1.h; ah[2]=p2.h; ah[3]=p3.h;
            ah[4]=p4.h; ah[5]=p5.h; ah[6]=p6.h; ah[7]=p7.h;
            al[0]=p0.l; al[1]=p1.l; al[2]=p2.l; al[3]=p3.l;
            al[4]=p4.l; al[5]=p5.l; al[6]=p6.l; al[7]=p7.l;
        }
#pragma unroll
        for (int nt = 0; nt < 4; ++nt) {
            int off = ((s * 64 + nt * 16 + ml) * 4 + q) * 8;
            bf16x8 bh = *reinterpret_cast<const bf16x8*>(BH + off);
            bf16x8 bl = *reinterpret_cast<const bf16x8*>(BL + off);
            acc[nt] = __builtin_amdgcn_mfma_f32_16x16x32_bf16(ah, bh, acc[nt], 0, 0, 0);
            acc[nt] = __builtin_amdgcn_mfma_f32_16x16x32_bf16(al, bh, acc[nt], 0, 0, 0);
            acc[nt] = __builtin_amdgcn_mfma_f32_16x16x32_bf16(ah, bl, acc[nt], 0, 0, 0);
        }
    }
    // epilogue: C/D layout col=lane&15, row=q*4+reg
#pragma unroll
    for (int reg = 0; reg < 4; ++reg) {
        int row = row0 + q * 4 + reg;
        int nid = go_nid[row];
#pragma unroll
        for (int nt = 0; nt < 4; ++nt) {
            int col = nt * 16 + ml;
            out[(size_t)row * 64 + col] = acc[nt][reg] + lin_b[col]
                + go_emb[(size_t)nid * 64 + col];
        }
    }
}

// ---------------- CSR build ----------------
__global__ void count_int(const int* __restrict__ dst, int* __restrict__ cnt, int nE) {
    int e = blockIdx.x * blockDim.x + threadIdx.x;
    if (e < nE) atomicAdd(&cnt[dst[e]], 1);
}

__global__ __launch_bounds__(1024) void scan_local(const int* __restrict__ cnt,
        int* __restrict__ loc, int* __restrict__ bsum, int n) {
    __shared__ int sh[1024];
    int i = blockIdx.x * 1024 + threadIdx.x;
    int v = (i < n) ? cnt[i] : 0;
    sh[threadIdx.x] = v;
    __syncthreads();
    for (int off = 1; off < 1024; off <<= 1) {
        int t = (threadIdx.x >= off) ? sh[threadIdx.x - off] : 0;
        __syncthreads();
        sh[threadIdx.x] += t;
        __syncthreads();
    }
    if (i < n) loc[i] = sh[threadIdx.x] - v;
    if (threadIdx.x == 1023) bsum[blockIdx.x] = sh[1023];
}

__global__ __launch_bounds__(1024) void scan_bsum(int* __restrict__ bsum, int nb) {
    __shared__ int sh[1024];
    int v = (threadIdx.x < nb) ? bsum[threadIdx.x] : 0;
    sh[threadIdx.x] = v;
    __syncthreads();
    for (int off = 1; off < 1024; off <<= 1) {
        int t = (threadIdx.x >= off) ? sh[threadIdx.x - off] : 0;
        __syncthreads();
        sh[threadIdx.x] += t;
        __syncthreads();
    }
    if (threadIdx.x < nb) bsum[threadIdx.x] = sh[threadIdx.x] - v;
}

__global__ void scan_add(const int* __restrict__ loc, const int* __restrict__ bsum,
                         int* __restrict__ rowptr, int* __restrict__ cursor, int n, int total) {
    int i = blockIdx.x * blockDim.x + threadIdx.x;
    if (i < n) {
        int v = loc[i] + bsum[i >> 10];
        rowptr[i] = v;
        cursor[i] = v;
    }
    if (i == n) rowptr[n] = total;
}

__global__ void fill_csr(const int* __restrict__ src, const int* __restrict__ dst,
                         int* __restrict__ cursor, int* __restrict__ csr_src, int nE) {
    int e = blockIdx.x * blockDim.x + threadIdx.x;
    if (e >= nE) return;
    int slot = atomicAdd(&cursor[dst[e]], 1);
    csr_src[slot] = src[e];
}

// ---------------- aggregation: out[d] = mean over CSR edges of x[src] ----------
__global__ void aggregate_csr(const float* __restrict__ x, const int* __restrict__ rowptr,
                              const int* __restrict__ csr_src, float* __restrict__ out, int n) {
    int row = blockIdx.x * 4 + (threadIdx.x >> 6);
    if (row >= n) return;
    int lane = threadIdx.x & 63;
    int qg   = lane >> 4;
    int l16  = lane & 15;
    int s = rowptr[row], e = rowptr[row + 1];
    const float4* x4 = reinterpret_cast<const float4*>(x);
    float4 a0 = make_float4(0.f, 0.f, 0.f, 0.f);
    float4 a1 = make_float4(0.f, 0.f, 0.f, 0.f);
    int i = s + qg;
    for (; i + 4 < e; i += 8) {
        int s0 = csr_src[i];
        int s1 = csr_src[i + 4];
        float4 v0 = x4[(size_t)s0 * 16 + l16];
        float4 v1 = x4[(size_t)s1 * 16 + l16];
        a0.x += v0.x; a0.y += v0.y; a0.z += v0.z; a0.w += v0.w;
        a1.x += v1.x; a1.y += v1.y; a1.z += v1.z; a1.w += v1.w;
    }
    if (i < e) {
        int s0 = csr_src[i];
        float4 v0 = x4[(size_t)s0 * 16 + l16];
        a0.x += v0.x; a0.y += v0.y; a0.z += v0.z; a0.w += v0.w;
    }
    a0.x += a1.x; a0.y += a1.y; a0.z += a1.z; a0.w += a1.w;
    a0.x += __shfl_xor(a0.x, 16); a0.y += __shfl_xor(a0.y, 16);
    a0.z += __shfl_xor(a0.z, 16); a0.w += __shfl_xor(a0.w, 16);
    a0.x += __shfl_xor(a0.x, 32); a0.y += __shfl_xor(a0.y, 32);
    a0.z += __shfl_xor(a0.z, 32); a0.w += __shfl_xor(a0.w, 32);
    if (qg == 0) {
        float inv = (e > s) ? 1.0f / (float)(e - s) : 0.0f;
        float4 r = make_float4(a0.x * inv, a0.y * inv, a0.z * inv, a0.w * inv);
        reinterpret_cast<float4*>(out)[(size_t)row * 16 + l16] = r;
    }
}

// ---------------- node update: out = agg@Wl + bias + x@Wr (bf16x3 MFMA) ----
constexpr int LDA_UN = 72;
__global__ __launch_bounds__(256) void update_nodes_mfma(
        const float* agg, const float* __restrict__ x,
        const float* __restrict__ Wl, const float* __restrict__ bias,
        const float* __restrict__ Wr, float* out, int n, int relu) {
    __shared__ short Ah[64][LDA_UN], Al[64][LDA_UN];
    __shared__ short Bh[64][LDA_UN], Bl[64][LDA_UN];
    int tid = threadIdx.x;
    int wave = tid >> 6, lane = tid & 63;
    int ml = lane & 15, q = lane >> 4;
    int row0 = blockIdx.x * 64;
    f32x4 acc[4] = {};
    for (int half = 0; half < 2; ++half) {
        const float* Xsrc = half ? x : agg;
        const float* Wsrc = half ? Wr : Wl;
        {
            int k4 = tid & 15;
            for (int r = tid >> 4; r < 64; r += 16) {
                int grow = row0 + r; if (grow >= n) grow = n - 1;
                float4 v = *reinterpret_cast<const float4*>(&Xsrc[(size_t)grow * 64 + k4 * 4]);
                s16x4 h, l;
                BfPair p0 = split_bf(v.x), p1 = split_bf(v.y),
                       p2 = split_bf(v.z), p3 = split_bf(v.w);
                h[0] = p0.h; h[1] = p1.h; h[2] = p2.h; h[3] = p3.h;
                l[0] = p0.l; l[1] = p1.l; l[2] = p2.l; l[3] = p3.l;
                *reinterpret_cast<s16x4*>(&Ah[r][k4 * 4]) = h;
                *reinterpret_cast<s16x4*>(&Al[r][k4 * 4]) = l;
            }
        }
        {
            int nn = tid & 63;
            for (int kr = tid >> 6; kr < 64; kr += 4) {
                float v = Wsrc[(size_t)kr * 64 + nn];
                BfPair p = split_bf(v);
                Bh[nn][kr] = p.h; Bl[nn][kr] = p.l;
            }
        }
        __syncthreads();
#pragma unroll
        for (int kc = 0; kc < 64; kc += 32) {
            int kb = kc + q * 8;
            int m = wave * 16 + ml;
            bf16x8 ah = *reinterpret_cast<const bf16x8*>(&Ah[m][kb]);
            bf16x8 al = *reinterpret_cast<const bf16x8*>(&Al[m][kb]);
#pragma unroll
            for (int nt = 0; nt < 4; ++nt) {
                int nn = nt * 16 + ml;
                bf16x8 bh = *reinterpret_cast<const bf16x8*>(&Bh[nn][kb]);
                bf16x8 bl = *reinterpret_cast<const bf16x8*>(&Bl[nn][kb]);
                acc[nt] = __builtin_amdgcn_mfma_f32_16x16x32_bf16(ah, bh, acc[nt], 0, 0, 0);
                acc[nt] = __builtin_amdgcn_mfma_f32_16x16x32_bf16(al, bh, acc[nt], 0, 0, 0);
                acc[nt] = __builtin_amdgcn_mfma_f32_16x16x32_bf16(ah, bl, acc[nt], 0, 0, 0);
            }
        }
        __syncthreads();
    }
#pragma unroll
    for (int reg = 0; reg < 4; ++reg) {
        int row = row0 + wave * 16 + q * 4 + reg;
        if (row >= n) continue;
#pragma unroll
        for (int nt = 0; nt < 4; ++nt) {
            int col = nt * 16 + ml;
            float v = acc[nt][reg] + bias[col];
            if (relu) v = fmaxf(v, 0.0f);
            out[(size_t)row * 64 + col] = v;
        }
    }
}

// ---------------- classifier ----------------
__global__ void classify(const float* __restrict__ xp, const float* __restrict__ xg,
                         const int* __restrict__ ls, const int* __restrict__ ld,
                         float* __restrict__ out, int nE) {
    int t = blockIdx.x * blockDim.x + threadIdx.x;
    int e = t >> 4;
    int l16 = t & 15;
    if (e >= nE) return;
    int s = ls[e], d = ld[e];
    float4 a = reinterpret_cast<const float4*>(xp)[(size_t)s * 16 + l16];
    float4 b = reinterpret_cast<const float4*>(xg)[(size_t)d * 16 + l16];
    float v = a.x * b.x + a.y * b.y + a.z * b.z + a.w * b.w;
    v += __shfl_xor(v, 8);
    v += __shfl_xor(v, 4);
    v += __shfl_xor(v, 2);
    v += __shfl_xor(v, 1);
    if (l16 == 0) out[e] = v;
}

extern "C" void kernel_launch(void* const* d_in, const int* in_sizes, int n_in,
                              void* d_out, int out_size, void* d_ws, size_t ws_size,
                              hipStream_t stream) {
    const float* go_x        = (const float*)d_in[0];
    const float* protein_emb = (const float*)d_in[1];
    const float* go_emb      = (const float*)d_in[2];
    const float* lin_W       = (const float*)d_in[3];
    const float* lin_b       = (const float*)d_in[4];
    const float* Wl          = (const float*)d_in[5];
    const float* bl          = (const float*)d_in[6];
    const float* Wr          = (const float*)d_in[7];
    const int* protein_nid   = (const int*)d_in[8];
    const int* go_nid        = (const int*)d_in[9];
    const int* src_pg        = (const int*)d_in[10];
    const int* dst_pg        = (const int*)d_in[11];
    const int* src_gp        = (const int*)d_in[12];
    const int* dst_gp        = (const int*)d_in[13];
    const int* label_src     = (const int*)d_in[14];
    const int* label_dst     = (const int*)d_in[15];
    float* out = (float*)d_out;

    float* ws = (float*)d_ws;
    float* p0 = ws;
    float* p1 = p0 + (size_t)N_P * 64;
    float* g0 = p1 + (size_t)N_P * 64;
    float* g1 = g0 + (size_t)N_G * 64;
    int* ib = (int*)(g1 + (size_t)N_G * 64);
    int* rowptr_g = ib;                 ib += N_G + 1;
    int* cursor_g = ib;                 ib += N_G + 1;
    int* rowptr_p = ib;                 ib += N_P + 1;
    int* cursor_p = ib;                 ib += N_P + 1;
    int* cnt_i    = ib;                 ib += N_P;
    int* loc      = ib;                 ib += N_P;
    int* bsum     = ib;                 ib += 1024;
    int* csr_g    = ib;                 ib += NE;
    int* csr_p    = ib;                 ib += NE;
    short* BfragH = (short*)ib;         // 32*64*4*8 = 65536 shorts
    short* BfragL = BfragH + KSTEPS * 64 * 4 * 8;

    gather_rows<<<(N_P * (DD / 4) + 255) / 256, 256, 0, stream>>>(protein_emb, protein_nid, p0, N_P);
    pack_B<<<(KSTEPS * 64 * 4 + 255) / 256, 256, 0, stream>>>(lin_W, BfragH, BfragL);
    lin_go_mfma<<<N_G / 64, 256, 0, stream>>>(go_x, BfragH, BfragL, lin_b, go_emb, go_nid, g0);

    hipMemsetAsync(cnt_i, 0, (size_t)N_G * sizeof(int), stream);
    count_int<<<(NE + 255) / 256, 256, 0, stream>>>(dst_pg, cnt_i, NE);
    scan_local<<<(N_G + 1023) / 1024, 1024, 0, stream>>>(cnt_i, loc, bsum, N_G);
    scan_bsum<<<1, 1024, 0, stream>>>(bsum, (N_G + 1023) / 1024);
    scan_add<<<(N_G + 256) / 256, 256, 0, stream>>>(loc, bsum, rowptr_g, cursor_g, N_G, NE);
    fill_csr<<<(NE + 255) / 256, 256, 0, stream>>>(src_pg, dst_pg, cursor_g, csr_g, NE);

    hipMemsetAsync(cnt_i, 0, (size_t)N_P * sizeof(int), stream);
    count_int<<<(NE + 255) / 256, 256, 0, stream>>>(dst_gp, cnt_i, NE);
    scan_local<<<(N_P + 1023) / 1024, 1024, 0, stream>>>(cnt_i, loc, bsum, N_P);
    scan_bsum<<<1, 1024, 0, stream>>>(bsum, (N_P + 1023) / 1024);
    scan_add<<<(N_P + 256) / 256, 256, 0, stream>>>(loc, bsum, rowptr_p, cursor_p, N_P, NE);
    fill_csr<<<(NE + 255) / 256, 256, 0, stream>>>(src_gp, dst_gp, cursor_p, csr_p, NE);

    float* xp = p0; float* xg = g0; float* sp = p1; float* sg = g1;
    for (int l = 0; l < 3; ++l) {
        aggregate_csr<<<(N_G + 3) / 4, 256, 0, stream>>>(xp, rowptr_g, csr_g, sg, N_G);
        aggregate_csr<<<(N_P + 3) / 4, 256, 0, stream>>>(xg, rowptr_p, csr_p, sp, N_P);
        int relu = (l < 2) ? 1 : 0;
        const float* wl0 = Wl + (size_t)(l * 2 + 0) * 4096;
        const float* wl1 = Wl + (size_t)(l * 2 + 1) * 4096;
        const float* wr0 = Wr + (size_t)(l * 2 + 0) * 4096;
        const float* wr1 = Wr + (size_t)(l * 2 + 1) * 4096;
        const float* b0  = bl + (size_t)(l * 2 + 0) * 64;
        const float* b1  = bl + (size_t)(l * 2 + 1) * 64;
        update_nodes_mfma<<<(N_G + 63) / 64, 256, 0, stream>>>(sg, xg, wl0, b0, wr0, sg, N_G, relu);
        update_nodes_mfma<<<(N_P + 63) / 64, 256, 0, stream>>>(sp, xp, wl1, b1, wr1, sp, N_P, relu);
        float* t;
        t = xp; xp = sp; sp = t;
        t = xg; xg = sg; sg = t;
    }
    classify<<<(E_LBL * 16 + 255) / 256, 256, 0, stream>>>(xp, xg, label_src, label_dst, out, E_LBL);
}